// Round 1
// 4386.226 us; speedup vs baseline: 1.4976x; 1.4976x over previous
//
#include <hip/hip_runtime.h>
#include <hip/hip_bf16.h>

typedef __hip_bfloat16 bf16;
typedef __attribute__((ext_vector_type(8))) short short8v;
typedef __attribute__((ext_vector_type(4))) float f32x4;

// Problem constants: B=256, T=1024, D=256, H=16, C=64, nch=16, qk_h=v_h=16,
// batchsize=8, ENC_IN=32, D_FF=512.

// ---------------- ws layout (byte offsets) ----------------
static const size_t OFF_QKV  = 0;
static const size_t OFF_Z    = 0;
static const size_t OFF_XGAT = 268435456ULL;
static const size_t OFF_RET  = 402653184ULL;   // f32[67108864]
static const size_t OFF_XKV  = 671088640ULL;   // f32[16777216]; alias ms/rs later
static const size_t OFF_MS   = 671088640ULL;   // f32[4194304]
static const size_t OFF_RS   = 687865856ULL;   // f32[4194304]
static const size_t OFF_PKV  = 738197504ULL;   // f32[16777216]; alias xbar later
static const size_t OFF_XBAR = 738197504ULL;   // f32[8388608]
static const size_t OFF_TAB  = 805306368ULL;   // f32[524288]
static const size_t OFF_U    = 807403520ULL;   // f32[65536]
static const size_t OFF_S2   = 807665664ULL;   // f32[65536]
static const size_t OFF_P    = 807927808ULL;   // f32[65536]
static const size_t OFF_GBAR = 808189952ULL;   // f32[524288]
static const size_t OFF_TEMP = 810287104ULL;   // f32[65536]
static const size_t OFF_GI   = 810549248ULL;   // f32[196608]
static const size_t OFF_HST  = 811335680ULL;   // f32[4096]

// ---------------- xpos cos/sin table ----------------
__global__ __launch_bounds__(256) void k_xpos_table(float4* __restrict__ tab) {
  int i = blockIdx.x * 256 + threadIdx.x;   // 131072 = 1024 t x 128 j
  int t = i >> 7, j = i & 127;
  float base = (2.f * (float)j + 102.4f) * (1.f / 358.4f);
  float sc   = powf(base, (float)t * (1.f / 512.f));
  float invf = powf(10000.f, -(float)j * (1.f / 128.f));
  float ang  = (float)t * invf;
  float cv = cosf(ang), sv = sinf(ang);
  tab[i] = make_float4(cv * sc, sv * sc, cv / sc, sv / sc);
}

// ================= MFMA bf16 GEMM: C = A(MxK,f32) * B(NxK,f32)^T ==========
// 128x128 tile, 4 waves, BK=32, reg-staged fp32->bf16, fragment-major LDS
// (lane-linear ds_read_b128, conflict-free). XCD-chunked block swizzle with
// N-tile fastest so A panels stay resident in one XCD's L2.

__device__ __forceinline__ short f2bf(float x) {
  union { __hip_bfloat16 b; short s; } u;
  u.b = __float2bfloat16(x);
  return u.s;
}

// each thread loads 16 consecutive f32 (64B) of one row of a 128x32 tile
__device__ __forceinline__ void load_tile4(const float* __restrict__ P, long rowbase,
                                           int K, int k0, float4 (&r)[4], int tid) {
  const float* p = P + (rowbase + (tid >> 1)) * (long)K + k0 + ((tid & 1) << 4);
  r[0] = ((const float4*)p)[0];
  r[1] = ((const float4*)p)[1];
  r[2] = ((const float4*)p)[2];
  r[3] = ((const float4*)p)[3];
}

// fragment-major store: element (row, klow) -> chunk (row>>4)*64 + (klow>>3)*16
// + (row&15), j = klow&7.  Read side: lane l of frag m does one contiguous
// short8 at chunk m*64+l  => row = l&15, k = (l>>4)*8+j (A and B identical, so
// any k permutation cancels inside the MFMA dot product).
__device__ __forceinline__ void stage_frag(short* __restrict__ S, const float4 (&r)[4],
                                           int tid) {
  int row = tid >> 1, half = tid & 1;
  int m = row >> 4, rl = row & 15;
#pragma unroll
  for (int q = 0; q < 2; ++q) {
    float4 a = r[q * 2], b = r[q * 2 + 1];
    short8v v;
    v[0] = f2bf(a.x); v[1] = f2bf(a.y); v[2] = f2bf(a.z); v[3] = f2bf(a.w);
    v[4] = f2bf(b.x); v[5] = f2bf(b.y); v[6] = f2bf(b.z); v[7] = f2bf(b.w);
    int chunk = m * 64 + (half * 2 + q) * 16 + rl;
    *(short8v*)(S + chunk * 8) = v;
  }
}

template <typename Epi>
__global__ __launch_bounds__(256) void gemm_mfma(const float* __restrict__ A,
                                                 const float* __restrict__ B,
                                                 int K, int ntn, Epi epi) {
  __shared__ alignas(16) short As[4096];   // 8 KB
  __shared__ alignas(16) short Bs[4096];   // 8 KB
  const int tid = threadIdx.x;
  // bijective XCD-chunked swizzle (grid sizes here are all %8==0, but keep general)
  int nwg = gridDim.x, orig = blockIdx.x;
  int qd = nwg >> 3, rm = nwg & 7;
  int xcd = orig & 7, loc = orig >> 3;
  int swz = (xcd < rm) ? (xcd * (qd + 1) + loc)
                       : (rm * (qd + 1) + (xcd - rm) * qd + loc);
  long row0 = (long)(swz / ntn) * 128;
  long col0 = (long)(swz % ntn) * 128;

  const int lane = tid & 63;
  const int w = tid >> 6, wr = w >> 1, wc = w & 1;

  float4 ra[4], rb[4];
  load_tile4(A, row0, K, 0, ra, tid);
  load_tile4(B, col0, K, 0, rb, tid);
  f32x4 acc[4][4] = {};
  const int nk = K >> 5;
  for (int t = 0; t < nk; ++t) {
    stage_frag(As, ra, tid);
    stage_frag(Bs, rb, tid);
    __syncthreads();
    if (t + 1 < nk) {            // prefetch next K-tile while MFMAs run
      load_tile4(A, row0, K, (t + 1) << 5, ra, tid);
      load_tile4(B, col0, K, (t + 1) << 5, rb, tid);
    }
    short8v af[4], bfr[4];
#pragma unroll
    for (int mm = 0; mm < 4; ++mm)
      af[mm] = *(const short8v*)(As + ((wr * 4 + mm) * 64 + lane) * 8);
#pragma unroll
    for (int nn = 0; nn < 4; ++nn)
      bfr[nn] = *(const short8v*)(Bs + ((wc * 4 + nn) * 64 + lane) * 8);
#pragma unroll
    for (int mm = 0; mm < 4; ++mm)
#pragma unroll
      for (int nn = 0; nn < 4; ++nn)
        acc[mm][nn] = __builtin_amdgcn_mfma_f32_16x16x32_bf16(af[mm], bfr[nn],
                                                              acc[mm][nn], 0, 0, 0);
    __syncthreads();
  }
  // epilogue: C/D layout col = lane&15, row = (lane>>4)*4 + reg
  const long rb0 = row0 + wr * 64 + ((lane >> 4) << 2);
  const long cb0 = col0 + wc * 64 + (lane & 15);
#pragma unroll
  for (int mm = 0; mm < 4; ++mm)
#pragma unroll
    for (int nn = 0; nn < 4; ++nn)
#pragma unroll
      for (int rg = 0; rg < 4; ++rg) {
        float v = acc[mm][nn][rg];
        float vp = __shfl_xor(v, 1);   // partner column (c^1) value
        epi.apply(rb0 + mm * 16 + rg, cb0 + nn * 16, v, vp);
      }
}

// qkv epilogue: xpos to q (cols 0..255, upscale) and k (256..511, downscale),
// pass-through v; store bf16 into qkv (B*T, 768).
struct EpiXposM {
  bf16* qkv; const float4* tab;
  __device__ void apply(long r, long c, float v, float vp) const {
    int t = (int)(r & 1023);
    float o = v;
    if (c < 512) {
      int j = ((int)c & 255) >> 1;
      float4 tb = tab[(t << 7) + j];
      float cv = (c < 256) ? tb.x : tb.z;
      float sv = (c < 256) ? tb.y : tb.w;
      o = (c & 1) ? (v * cv + vp * sv) : (v * cv - vp * sv);
    }
    qkv[r * 768 + c] = __float2bfloat16(o);
  }
};

// gat_in epilogue: rows r = n*4096 + b*16 + h; store x[n][b][h*256+c]
struct EpiGatInM {
  float* x;
  __device__ void apply(long r, long c, float v, float) const {
    long n = r >> 12, b = (r >> 4) & 255, h = r & 15;
    x[((((n << 8) + b) << 12)) + (h << 8) + c] = v;
  }
};

// Z epilogue: Z = silu(gated) * groupnorm(retention_out)
struct EpiZM {
  float* Z; const float* ret; const float* ms; const float* rs;
  __device__ void apply(long r, long c, float v, float) const {
    long b = r >> 10, t = r & 1023, n = t >> 6, cc = t & 63;
    long h = c >> 4, vv = c & 15;
    long s = (((n * 256 + b) * 16 + h) * 64 + cc);
    float sig = 1.f / (1.f + expf(-v));
    Z[r * 256 + c] = v * sig * (ret[s * 16 + vv] - ms[s]) * rs[s];
  }
};

struct EpiPlainM {
  float* C; long ldc;
  __device__ void apply(long r, long c, float v, float) const {
    C[r * ldc + c] = v;
  }
};

// ---------------- generic tiled GEMM (fp32 VALU) — kept for the two tiny GEMMs
template <typename Epi>
__global__ __launch_bounds__(256) void gemm64(const float* __restrict__ A,
                                              const float* __restrict__ B,
                                              int M, int N, int K, Epi epi) {
  __shared__ float As[16][68];
  __shared__ float Bs[16][68];
  const int tid = threadIdx.x;
  const long row0 = (long)blockIdx.x * 64;
  const long col0 = (long)blockIdx.y * 64;
  const int lr = tid >> 2;
  const int lk = (tid & 3) << 2;
  const int ty = tid >> 4, tx = tid & 15;
  float acc[4][4] = {};
  const float* Ap = A + (row0 + lr) * (long)K + lk;
  const float* Bp = B + (col0 + lr) * (long)K + lk;
  for (int k0 = 0; k0 < K; k0 += 16) {
    float4 a4 = *(const float4*)(Ap + k0);
    float4 b4 = *(const float4*)(Bp + k0);
    As[lk + 0][lr] = a4.x; As[lk + 1][lr] = a4.y;
    As[lk + 2][lr] = a4.z; As[lk + 3][lr] = a4.w;
    Bs[lk + 0][lr] = b4.x; Bs[lk + 1][lr] = b4.y;
    Bs[lk + 2][lr] = b4.z; Bs[lk + 3][lr] = b4.w;
    __syncthreads();
#pragma unroll
    for (int k = 0; k < 16; ++k) {
      float4 av = *(const float4*)&As[k][ty << 2];
      float4 bv = *(const float4*)&Bs[k][tx << 2];
      float a[4] = {av.x, av.y, av.z, av.w};
      float b[4] = {bv.x, bv.y, bv.z, bv.w};
#pragma unroll
      for (int ii = 0; ii < 4; ++ii)
#pragma unroll
        for (int jj = 0; jj < 4; ++jj)
          acc[ii][jj] = fmaf(a[ii], b[jj], acc[ii][jj]);
    }
    __syncthreads();
  }
  epi.apply(row0 + (ty << 2), col0 + (tx << 2), acc);
}

struct EpiPlain {
  float* C; long ldc;
  __device__ void apply(long r0, long c0, const float (&acc)[4][4]) const {
#pragma unroll
    for (int i = 0; i < 4; ++i)
#pragma unroll
      for (int j = 0; j < 4; ++j)
        C[(r0 + i) * ldc + c0 + j] = acc[i][j];
  }
};

// ---------------- per-chunk decayed kv outer product ----------------
__global__ __launch_bounds__(256) void k_kv_outer(const bf16* __restrict__ qkv,
                                                  float* __restrict__ X) {
  int blk = blockIdx.x;                 // n*4096 + b*16 + h
  int h = blk & 15, b = (blk >> 4) & 255, n = blk >> 12;
  __shared__ float ks[64][16], vs[64][16], intra[64];
  int tid = threadIdx.x;
  for (int idx = tid; idx < 1024; idx += 256) {
    int c = idx >> 4, d = idx & 15;
    long base = ((long)(b * 1024 + n * 64 + c)) * 768 + h * 16;
    ks[c][d] = __bfloat162float(qkv[base + 256 + d]);
    vs[c][d] = __bfloat162float(qkv[base + 512 + d]);
  }
  if (tid < 64) {
    float gamma = 1.f - exp2f(-5.f - (float)h);
    intra[tid] = powf(gamma, (float)(63 - tid));
  }
  __syncthreads();
  int d = tid >> 4, v = tid & 15;
  float acc = 0.f;
#pragma unroll
  for (int c = 0; c < 64; ++c) acc += ks[c][d] * vs[c][v] * intra[c];
  X[(long)blk * 256 + d * 16 + v] = acc;
}

// ---------------- prefix scan of kv state over 16 chunks ----------------
__global__ __launch_bounds__(256) void k_kv_scan(const float* __restrict__ X,
                                                 float* __restrict__ pastkv,
                                                 float* __restrict__ out1) {
  long i = (long)blockIdx.x * 256 + threadIdx.x;
  int h = ((int)i >> 8) & 15;
  float gamma = 1.f - exp2f(-5.f - (float)h);
  float cd = powf(gamma, 64.f);
  float pkv = 0.f;
  for (int n = 0; n < 16; ++n) {
    pastkv[(long)n * 1048576 + i] = pkv;
    pkv = cd * pkv + X[(long)n * 1048576 + i];
  }
  out1[i] = pkv;
}

// ---------------- retention: out = (qk^T*mask)v + q*pastkv*decay ----------
__global__ __launch_bounds__(64) void k_retention(const bf16* __restrict__ qkv,
                                                  const float* __restrict__ pastkv,
                                                  float* __restrict__ ret) {
  int blk = blockIdx.x;
  int h = blk & 15, b = (blk >> 4) & 255, n = blk >> 12;
  __shared__ float qs[64][17], ks[64][17], vs[64][17], pk[16][16], gpow[65];
  int tid = threadIdx.x;
  for (int idx = tid; idx < 1024; idx += 64) {
    int c = idx >> 4, d = idx & 15;
    long base = ((long)(b * 1024 + n * 64 + c)) * 768 + h * 16;
    qs[c][d] = __bfloat162float(qkv[base + d]);
    ks[c][d] = __bfloat162float(qkv[base + 256 + d]);
    vs[c][d] = __bfloat162float(qkv[base + 512 + d]);
  }
  {
    float gamma = 1.f - exp2f(-5.f - (float)h);
    gpow[tid] = powf(gamma, (float)tid);
    if (tid == 0) gpow[64] = powf(gamma, 64.f);
  }
  for (int idx = tid; idx < 256; idx += 64)
    pk[idx >> 4][idx & 15] = pastkv[(long)blk * 256 + idx];
  __syncthreads();
  int c = tid;
  float acc[16];
#pragma unroll
  for (int v = 0; v < 16; ++v) acc[v] = 0.f;
  for (int e = 0; e <= c; ++e) {
    float s = 0.f;
#pragma unroll
    for (int d = 0; d < 16; ++d) s += qs[c][d] * ks[e][d];
    float w = s * 0.25f * gpow[c - e];
#pragma unroll
    for (int v = 0; v < 16; ++v) acc[v] += w * vs[e][v];
  }
  float w2 = gpow[c + 1] * 0.25f;
#pragma unroll
  for (int v = 0; v < 16; ++v) {
    float s = 0.f;
#pragma unroll
    for (int d = 0; d < 16; ++d) s += qs[c][d] * pk[d][v];
    acc[v] += s * w2;
  }
  long obase = (long)blk * 1024 + c * 16;
#pragma unroll
  for (int v = 0; v < 16; ++v) ret[obase + v] = acc[v];
}

// ---------------- u[h] = W_gat[h] @ a2[h] ----------------
__global__ __launch_bounds__(256) void k_u(const float* __restrict__ W_gat,
                                           const float* __restrict__ a_gat,
                                           float* __restrict__ u) {
  int i = blockIdx.x * 256 + threadIdx.x;
  int h = i >> 12;
  const float* wr = W_gat + (long)i * 256;
  const float* a2 = a_gat + h * 512 + 256;
  float s = 0.f;
  for (int o = 0; o < 256; ++o) s += wr[o] * a2[o];
  u[i] = s;
}

// ---------------- s2[n,h,b] = x[n,b,:] . u[h,:] ----------------
__global__ __launch_bounds__(256) void k_s2(const float* __restrict__ x,
                                            const float* __restrict__ u,
                                            float* __restrict__ s2) {
  int n = blockIdx.x >> 8, b = blockIdx.x & 255;
  __shared__ float xs[4096];
  const float* xr = x + (long)blockIdx.x * 4096;
  for (int i = threadIdx.x; i < 4096; i += 256) xs[i] = xr[i];
  __syncthreads();
  int h = threadIdx.x >> 4, part = threadIdx.x & 15;
  const float* ur = u + h * 4096 + part * 256;
  const float* xp = xs + part * 256;
  float s = 0.f;
  for (int i = 0; i < 256; ++i) s += xp[i] * ur[i];
  s += __shfl_down(s, 8);
  s += __shfl_down(s, 4);
  s += __shfl_down(s, 2);
  s += __shfl_down(s, 1);
  if (part == 0) s2[(n * 16 + h) * 256 + b] = s;
}

// ---------------- p = softmax over m of s2 group ----------------
__global__ __launch_bounds__(64) void k_softmax(const float* __restrict__ s2,
                                                float* __restrict__ p) {
  int g = blockIdx.x * 64 + threadIdx.x;
  if (g >= 2048) return;
  int b2 = g & 7, nh = g >> 3;
  const float* row = s2 + nh * 256 + b2 * 32;
  float m = -1e30f;
  for (int i = 0; i < 32; ++i) m = fmaxf(m, row[i]);
  float e[32], sum = 0.f;
  for (int i = 0; i < 32; ++i) { e[i] = expf(row[i] - m); sum += e[i]; }
  float inv = 1.f / sum;
  for (int i = 0; i < 32; ++i) p[g * 32 + i] = e[i] * inv;
}

// ---------------- xbar[n,h,b2,f] = sum_m p[m] * x[n, b2*32+m, f] ----------
__global__ __launch_bounds__(256) void k_xbar(const float* __restrict__ x,
                                              const float* __restrict__ p,
                                              float* __restrict__ xbar) {
  int ft = blockIdx.x & 15, b2 = (blockIdx.x >> 4) & 7, n = blockIdx.x >> 7;
  __shared__ float xs[32][256];
  __shared__ float ps[16][32];
  for (int i = threadIdx.x; i < 32 * 256; i += 256) {
    int m = i >> 8, f = i & 255;
    xs[m][f] = x[((long)(n * 256 + b2 * 32 + m)) * 4096 + ft * 256 + f];
  }
  for (int i = threadIdx.x; i < 512; i += 256) {
    int h = i >> 5, m = i & 31;
    ps[h][m] = p[((n * 16 + h) * 8 + b2) * 32 + m];
  }
  __syncthreads();
  int f = threadIdx.x;
  for (int h = 0; h < 16; ++h) {
    float s = 0.f;
#pragma unroll
    for (int m = 0; m < 32; ++m) s += ps[h][m] * xs[m][f];
    xbar[((long)((n * 16 + h) * 8 + b2)) * 4096 + ft * 256 + f] = s;
  }
}

// ---------------- gbar[n,b2,h*256+o] = relu(xbar[n,h,b2,:] @ W_gat[h]) -----
__global__ __launch_bounds__(256) void k_gbar(const float* __restrict__ xbar,
                                              const float* __restrict__ W_gat,
                                              float* __restrict__ gbar) {
  int ot = blockIdx.x & 3, h = (blockIdx.x >> 2) & 15, n = blockIdx.x >> 6;
  __shared__ float wt[64][65];
  __shared__ float xt[8][64];
  int o = threadIdx.x & 63, q = threadIdx.x >> 6;
  float acc0 = 0.f, acc1 = 0.f;
  for (int f0 = 0; f0 < 4096; f0 += 64) {
    for (int i = threadIdx.x; i < 4096; i += 256) {
      int fr = i >> 6, oc = i & 63;
      wt[fr][oc] = W_gat[((long)h * 4096 + f0 + fr) * 256 + ot * 64 + oc];
    }
    for (int i = threadIdx.x; i < 512; i += 256) {
      int br = i >> 6, fc = i & 63;
      xt[br][fc] = xbar[((long)((n * 16 + h) * 8 + br)) * 4096 + f0 + fc];
    }
    __syncthreads();
#pragma unroll
    for (int f = 0; f < 64; ++f) {
      float w = wt[f][o];
      acc0 += xt[q][f] * w;
      acc1 += xt[q + 4][f] * w;
    }
    __syncthreads();
  }
  gbar[((long)(n * 8 + q)) * 4096 + h * 256 + ot * 64 + o]     = fmaxf(acc0, 0.f);
  gbar[((long)(n * 8 + q + 4)) * 4096 + h * 256 + ot * 64 + o] = fmaxf(acc1, 0.f);
}

// ---------------- GRU step (state (8,512), sequential) ----------------
__global__ __launch_bounds__(512) void k_gru(const float* __restrict__ gi,
                                             const float* __restrict__ w_hh,
                                             const float* __restrict__ b_ih,
                                             const float* __restrict__ b_hh,
                                             float* __restrict__ hstate, int step) {
  int b2 = blockIdx.x;
  int j = threadIdx.x;
  __shared__ float hs[512];
  hs[j] = hstate[b2 * 512 + j];
  __syncthreads();
  const float* wr = w_hh + (long)j * 512;
  const float* wz = w_hh + (long)(512 + j) * 512;
  const float* wn = w_hh + (long)(1024 + j) * 512;
  float ghr = 0.f, ghz = 0.f, ghn = 0.f;
  for (int k = 0; k < 512; ++k) {
    float hv = hs[k];
    ghr += wr[k] * hv; ghz += wz[k] * hv; ghn += wn[k] * hv;
  }
  const float* gir = gi + ((long)(step * 8 + b2)) * 1536;
  float ir = gir[j] + b_ih[j];
  float iz = gir[512 + j] + b_ih[512 + j];
  float in_ = gir[1024 + j] + b_ih[1024 + j];
  float r = 1.f / (1.f + expf(-(ir + ghr + b_hh[j])));
  float z = 1.f / (1.f + expf(-(iz + ghz + b_hh[512 + j])));
  float nn = tanhf(in_ + r * (ghn + b_hh[1024 + j]));
  hstate[b2 * 512 + j] = (1.f - z) * nn + z * hs[j];
}

// ---------------- out2: broadcast final GRU state to (8,32,512) -----------
__global__ __launch_bounds__(256) void k_out2(const float* __restrict__ hstate,
                                              float* __restrict__ out2) {
  int i = blockIdx.x * 256 + threadIdx.x;
  int j = i & 511, b2 = i >> 14;
  out2[i] = hstate[b2 * 512 + j];
}

// ---------------- per-(b,t,h) mean / rstd of retention out ----------------
__global__ __launch_bounds__(256) void k_stats(const float* __restrict__ ret,
                                               float* __restrict__ ms,
                                               float* __restrict__ rs) {
  long i = (long)blockIdx.x * 256 + threadIdx.x;
  const float* g = ret + i * 16;
  float s = 0.f, s2 = 0.f;
#pragma unroll
  for (int v = 0; v < 16; ++v) { float x = g[v]; s += x; s2 += x * x; }
  float mean = s * (1.f / 16.f);
  float var = s2 * (1.f / 16.f) - mean * mean;
  ms[i] = mean;
  rs[i] = rsqrtf(fmaxf(var, 0.f) + 1e-5f);
}

extern "C" void kernel_launch(void* const* d_in, const int* in_sizes, int n_in,
                              void* d_out, int out_size, void* d_ws, size_t ws_size,
                              hipStream_t stream) {
  const float* hidden       = (const float*)d_in[0];
  const float* W_qkv        = (const float*)d_in[1];
  const float* W_gated      = (const float*)d_in[2];
  const float* W_proj       = (const float*)d_in[3];
  const float* W_gat_proj   = (const float*)d_in[4];
  const float* W_gat_linear = (const float*)d_in[5];
  const float* W_gat        = (const float*)d_in[6];
  const float* a_gat        = (const float*)d_in[7];
  const float* w_ih         = (const float*)d_in[8];
  const float* w_hh         = (const float*)d_in[9];
  const float* b_ih         = (const float*)d_in[10];
  const float* b_hh         = (const float*)d_in[11];

  char* ws = (char*)d_ws;
  bf16*  qkv    = (bf16*)(ws + OFF_QKV);
  float* Zbuf   = (float*)(ws + OFF_Z);
  float* xgat   = (float*)(ws + OFF_XGAT);
  float* retb   = (float*)(ws + OFF_RET);
  float* Xkv    = (float*)(ws + OFF_XKV);
  float* ms     = (float*)(ws + OFF_MS);
  float* rs     = (float*)(ws + OFF_RS);
  float* pastkv = (float*)(ws + OFF_PKV);
  float* xbar   = (float*)(ws + OFF_XBAR);
  float* tab    = (float*)(ws + OFF_TAB);
  float* u      = (float*)(ws + OFF_U);
  float* s2     = (float*)(ws + OFF_S2);
  float* p      = (float*)(ws + OFF_P);
  float* gbar   = (float*)(ws + OFF_GBAR);
  float* temp   = (float*)(ws + OFF_TEMP);
  float* gi     = (float*)(ws + OFF_GI);
  float* hstate = (float*)(ws + OFF_HST);

  float* out0 = (float*)d_out;
  float* out1 = out0 + 67108864;   // cur_kv (256,16,16,16)
  float* out2 = out0 + 68157440;   // past_gat (8,32,512)

  // 1. xpos table
  k_xpos_table<<<512, 256, 0, stream>>>((float4*)tab);
  // 2. qkv GEMM (MFMA bf16) + xpos epilogue -> qkv bf16
  {
    EpiXposM e{qkv, (const float4*)tab};
    gemm_mfma<EpiXposM><<<2048 * 6, 256, 0, stream>>>(hidden, W_qkv, 256, 6, e);
  }
  // 3. per-chunk decayed kv outer products
  k_kv_outer<<<65536, 256, 0, stream>>>(qkv, Xkv);
  // 4. prefix scan over chunks; writes out1 (cur_kv)
  k_kv_scan<<<4096, 256, 0, stream>>>(Xkv, pastkv, out1);
  // 5. retention per chunk
  k_retention<<<65536, 64, 0, stream>>>(qkv, pastkv, retb);
  // 6. gat_in GEMM (MFMA bf16, retout viewed as (65536,1024))
  {
    EpiGatInM e{xgat};
    gemm_mfma<EpiGatInM><<<512 * 2, 256, 0, stream>>>(retb, W_gat_proj, 1024, 2, e);
  }
  // 7. GAT degenerate-attention path
  k_u<<<256, 256, 0, stream>>>(W_gat, a_gat, u);
  k_s2<<<4096, 256, 0, stream>>>(xgat, u, s2);
  k_softmax<<<32, 64, 0, stream>>>(s2, p);
  k_xbar<<<2048, 256, 0, stream>>>(xgat, p, xbar);
  k_gbar<<<1024, 256, 0, stream>>>(xbar, W_gat, gbar);
  // 8. temp = gbar @ W_gat_linear^T  (128 x 4096 -> 512)
  {
    EpiPlain e{temp, 512};
    gemm64<EpiPlain><<<dim3(2, 8), 256, 0, stream>>>(gbar, W_gat_linear, 128, 512, 4096, e);
  }
  // 9. gi = temp @ w_ih^T (biases added in GRU step)
  {
    EpiPlain e{gi, 1536};
    gemm64<EpiPlain><<<dim3(2, 24), 256, 0, stream>>>(temp, w_ih, 128, 1536, 512, e);
  }
  // 10. GRU chain: h0 = temp[chunk 0]
  hipMemcpyAsync(hstate, temp, 8 * 512 * sizeof(float), hipMemcpyDeviceToDevice, stream);
  for (int st = 1; st < 16; ++st)
    k_gru<<<8, 512, 0, stream>>>(gi, w_hh, b_ih, b_hh, hstate, st);
  k_out2<<<512, 256, 0, stream>>>(hstate, out2);
  // 11. group-norm stats
  k_stats<<<16384, 256, 0, stream>>>(retb, ms, rs);
  // 12. Z = silu(hidden @ W_gated^T) * normed  (MFMA bf16)
  {
    EpiZM e{Zbuf, retb, ms, rs};
    gemm_mfma<EpiZM><<<2048 * 2, 256, 0, stream>>>(hidden, W_gated, 256, 2, e);
  }
  // 13. out0 = Z @ W_proj^T  (MFMA bf16)
  {
    EpiPlainM e{out0, 256};
    gemm_mfma<EpiPlainM><<<2048 * 2, 256, 0, stream>>>(Zbuf, W_proj, 256, 2, e);
  }
}